// Round 10
// baseline (357.996 us; speedup 1.0000x reference)
//
#include <hip/hip_runtime.h>

typedef unsigned short u16;
typedef unsigned short u16x8 __attribute__((ext_vector_type(8)));
typedef __bf16 bf16x8 __attribute__((ext_vector_type(8)));
typedef float f32x4 __attribute__((ext_vector_type(4)));

#define HW 3136        // 56*56
#define NPIX 100352    // 32*3136
#define PADR 3364      // 58*58 padded rows per image
#define KD 1152        // 9*128
#define NBLK 784

__device__ __forceinline__ float bf2f(u16 u) {
    unsigned int x = ((unsigned int)u) << 16;
    return __builtin_bit_cast(float, x);
}
__device__ __forceinline__ u16 f2bf(float f) {
    unsigned int u = __builtin_bit_cast(unsigned int, f);
    return (u16)((u + 0x7FFFu + ((u >> 16) & 1u)) >> 16);
}
__device__ __forceinline__ void gload16(const void* g, void* l) {
    __builtin_amdgcn_global_load_lds(
        (const __attribute__((address_space(1))) unsigned int*)g,
        (__attribute__((address_space(3))) unsigned int*)l, 16, 0, 0);
}

// ---- setup: binarize weights + zero xbp AND out1p borders + zero counters ----
__global__ void setup_kernel(const float* __restrict__ w1, const float* __restrict__ w2,
                             u16* __restrict__ Bm1, u16* __restrict__ Bm2,
                             u16* __restrict__ xbp, u16* __restrict__ out1p,
                             int* __restrict__ counters) {
    const int b = blockIdx.x;
    const int t = threadIdx.x;
    if (b == 2064) {
        if (t < 2) counters[t] = 0;
        return;
    }
    if (b < 1152) {
        const float* w = (b < 576) ? w1 : w2;
        u16* Bm = (b < 576) ? Bm1 : Bm2;
        int i = (b % 576) * 256 + t;
        int k  = i / KD;
        int kk = i - k * KD;
        int c  = kk & 127;
        int rs = kk >> 7;
        float v = w[(size_t)(k * 128 + c) * 9 + rs];
        float sv = (v > 0.f) ? 1.f : ((v < 0.f) ? -1.f : 0.f);
        Bm[i] = f2bf(sv);
    } else {
        const bool toOut = (b >= 1608);
        u16* dst = toOut ? out1p : xbp;
        int idx = ((toOut ? b - 1608 : b - 1152)) * 256 + t;   // < 116736 exactly
        int pix = idx >> 4;
        int cc  = idx & 15;
        int n  = pix / 228;
        int pb = pix - n * 228;
        int h, w;
        if (pb < 58)       { h = 0;  w = pb; }
        else if (pb < 116) { h = 57; w = pb - 58; }
        else { int q = pb - 116; h = 1 + (q >> 1); w = (q & 1) ? 57 : 0; }
        u16x8 z = {};
        *(u16x8*)(dst + ((size_t)(n * PADR + h * 58 + w)) * 128 + cc * 8) = z;
    }
}

// ---- NCHW f32 -> padded NHWC bf16 (interior only) ----
__global__ void x_to_nhwc(const float* __restrict__ x, u16* __restrict__ xbp) {
    __shared__ float tile[32][65];
    const int t = threadIdx.x;
    const int n = blockIdx.y;
    const int ct = blockIdx.x & 3;
    const int pt = blockIdx.x >> 2;
    const int c0 = ct * 32, p0 = pt * 64;
    {
        const int c  = t >> 3;
        const int pw = (t & 7) * 8;
        const size_t ib = ((size_t)(n * 128 + c0 + c)) * HW + p0 + pw;
        const float4 v0 = *(const float4*)(x + ib);
        const float4 v1 = *(const float4*)(x + ib + 4);
        tile[c][pw + 0] = v0.x; tile[c][pw + 1] = v0.y;
        tile[c][pw + 2] = v0.z; tile[c][pw + 3] = v0.w;
        tile[c][pw + 4] = v1.x; tile[c][pw + 5] = v1.y;
        tile[c][pw + 6] = v1.z; tile[c][pw + 7] = v1.w;
    }
    __syncthreads();
    {
        const int pl = t >> 2;
        const int cs = (t & 3) * 8;
        const int p  = p0 + pl;
        const int h  = p / 56;
        const int w  = p - h * 56;
        u16x8 o;
#pragma unroll
        for (int j = 0; j < 8; ++j) o[j] = f2bf(tile[cs + j][pl]);
        *(u16x8*)(xbp + ((size_t)(n * PADR + (h + 1) * 58 + (w + 1))) * 128 + c0 + cs) = o;
    }
}

// ---- conv implicit GEMM (R5 core) + last-block BN-coef finalize ----
__global__ __launch_bounds__(256, 4) void conv_mfma(
    const u16* __restrict__ xbp, const u16* __restrict__ Bm,
    u16* __restrict__ y, float2* __restrict__ partial,
    const float* __restrict__ gamma, const float* __restrict__ beta,
    float2* __restrict__ coef, int* __restrict__ counter)
{
    __shared__ __align__(16) u16 smem[20480];   // 40960 B -> 4 blocks/CU
    u16* As = smem;            // [128 rows][64 ch] = 16 KB
    u16* Bs = smem + 8192;     // [128 rows][64 ch] = 16 KB
    const int t = threadIdx.x;
    const int bid0 = blockIdx.x;
    const int bid = (bid0 & 7) * 98 + (bid0 >> 3);   // XCD swizzle, 784 = 8*98 bijective
    const int pm0 = bid * 128;
    const int wid  = t >> 6;
    const int lane = t & 63;
    const int lrow = lane & 15;
    const int lhk  = lane >> 4;
    const int m0 = (wid >> 1) * 64;
    const int n0 = (wid & 1) * 64;

    // staging: instr j covers 8-row group g=wid*4+j; lane -> row g*8+(lane>>3),
    // dest chunk lane&7 (linear), source chunk (lane&7)^(lane>>3) (inverse swizzle)
    const int rsub = lane >> 3;
    const int csrc = (lane & 7) ^ rsub;
    int apix[4], bbase[4];
#pragma unroll
    for (int j = 0; j < 4; ++j) {
        int row = (wid * 4 + j) * 8 + rsub;
        int ps  = pm0 + row;
        int n   = ps / HW;
        int rem = ps - n * HW;
        int h   = rem / 56;
        int w   = rem - h * 56;
        apix[j]  = (n * PADR + (h + 1) * 58 + (w + 1)) * 128 + csrc * 8;
        bbase[j] = row * KD + csrc * 8;
    }

    f32x4 acc[4][4] = {};

#pragma unroll 1
    for (int pp = 0; pp < 18; ++pp) {
        const int rs_ = pp >> 1;
        const int r_ = rs_ / 3, s_ = rs_ - r_ * 3;
        const int ash = ((r_ - 1) * 58 + (s_ - 1)) * 128 + (pp & 1) * 64;
        const int bsh = pp * 64;
#pragma unroll
        for (int j = 0; j < 4; ++j) {
            gload16(xbp + apix[j] + ash, As + (wid * 4 + j) * 512);
            gload16(Bm + bbase[j] + bsh, Bs + (wid * 4 + j) * 512);
        }
        __syncthreads();
#pragma unroll
        for (int kc = 0; kc < 2; ++kc) {
            bf16x8 af[4], bv[4];
#pragma unroll
            for (int mi = 0; mi < 4; ++mi) {
                int ck = (((kc << 2) | lhk) ^ (lrow & 7)) << 3;
                af[mi] = *(const bf16x8*)&As[(m0 + mi * 16 + lrow) * 64 + ck];
            }
#pragma unroll
            for (int ni = 0; ni < 4; ++ni) {
                int ck = (((kc << 2) | lhk) ^ (lrow & 7)) << 3;
                bv[ni] = *(const bf16x8*)&Bs[(n0 + ni * 16 + lrow) * 64 + ck];
            }
#pragma unroll
            for (int mi = 0; mi < 4; ++mi)
#pragma unroll
                for (int ni = 0; ni < 4; ++ni)
                    acc[mi][ni] = __builtin_amdgcn_mfma_f32_16x16x32_bf16(
                        af[mi], bv[ni], acc[mi][ni], 0, 0, 0);
        }
        __syncthreads();
    }

    // --- per-block BN stats
    float2* sred = (float2*)(smem + 17408);   // byte 34816..36863, past transpose tile
    {
        float sv[4], qv[4];
#pragma unroll
        for (int ni = 0; ni < 4; ++ni) {
            float a = 0.f, b = 0.f;
#pragma unroll
            for (int mi = 0; mi < 4; ++mi)
#pragma unroll
                for (int q = 0; q < 4; ++q) { float v = acc[mi][ni][q]; a += v; b += v * v; }
            a += __shfl_xor(a, 16); a += __shfl_xor(a, 32);
            b += __shfl_xor(b, 16); b += __shfl_xor(b, 32);
            sv[ni] = a; qv[ni] = b;
        }
        if (lane < 16) {
#pragma unroll
            for (int ni = 0; ni < 4; ++ni)
                sred[wid * 64 + ni * 16 + lane] = make_float2(sv[ni], qv[ni]);
        }
    }
    __syncthreads();
    if (t < 128) {
        const int ni = (t >> 4) & 3, oc = t & 15, hi = t >> 6;
        float2 u = sred[hi * 64 + ni * 16 + oc];
        float2 v = sred[(hi + 2) * 64 + ni * 16 + oc];
        partial[(size_t)t * NBLK + bid] = make_float2(u.x + v.x, u.y + v.y);
    }
    __threadfence();   // release partial (device scope) before counter bump later

    // --- transpose acc -> [128 px][136 pad] bf16 (34816 B), coalesced store
#pragma unroll
    for (int mi = 0; mi < 4; ++mi)
#pragma unroll
        for (int ni = 0; ni < 4; ++ni)
#pragma unroll
            for (int q = 0; q < 4; ++q)
                smem[(m0 + mi * 16 + lhk * 4 + q) * 136 + n0 + ni * 16 + lrow] =
                    f2bf(acc[mi][ni][q]);
    __syncthreads();
    {
        const int px = t >> 1, half = t & 1;
        const u16* src = &smem[px * 136 + half * 64];
        u16* dst = y + (size_t)(pm0 + px) * 128 + half * 64;
#pragma unroll
        for (int j = 0; j < 8; ++j)
            *(u16x8*)(dst + j * 8) = *(const u16x8*)(src + j * 8);
    }
    __syncthreads();   // all smem reads done before flag reuse

    // --- last-block BN coef finalize
    if (t == 0) smem[0] = (atomicAdd(counter, 1) == NBLK - 1) ? 1 : 0;
    __syncthreads();
    if (smem[0] == 0) return;
    __syncthreads();
    __threadfence();   // acquire: see all blocks' partials across XCDs
    {
        const int c = t >> 1;              // 0..127
        const float2* pc = partial + (size_t)c * NBLK + (t & 1) * 392;
        float s = 0.f, q = 0.f;
        for (int i = 0; i < 392; ++i) { float2 v = pc[i]; s += v.x; q += v.y; }
        float* fs = (float*)smem;          // 256 floats
        float* fq = fs + 256;
        fs[t] = s; fq[t] = q;
        __syncthreads();
        if (t < 128) {
            double ss = (double)fs[2 * t] + (double)fs[2 * t + 1];
            double qq = (double)fq[2 * t] + (double)fq[2 * t + 1];
            double mean = ss / (double)NPIX;
            double var  = qq / (double)NPIX - mean * mean;
            if (var < 0.0) var = 0.0;
            float inv = rsqrtf((float)var + 1e-5f);
            float a = gamma[t] * inv;
            coef[t] = make_float2(a, beta[t] - (float)mean * a);
        }
    }
}

// ---- BN1 + ReLU: y (linear NHWC) -> padded NHWC bf16 out1p (interior only) ----
__global__ void bnrelu_kernel(const u16* __restrict__ y, const float2* __restrict__ coef,
                              u16* __restrict__ out1p) {
    __shared__ float2 sc[128];
    const int t = threadIdx.x;
    if (t < 128) sc[t] = coef[t];
    __syncthreads();
    size_t i = (size_t)blockIdx.x * 256 + t;
    u16x8 v = *(const u16x8*)(y + i * 8);
    int p  = (int)(i >> 4);
    int c0 = (int)(i & 15) * 8;
    int n   = p / HW;
    int rem = p - n * HW;
    int h   = rem / 56;
    int w   = rem - h * 56;
    u16x8 o;
#pragma unroll
    for (int j = 0; j < 8; ++j) {
        float2 k = sc[c0 + j];
        o[j] = f2bf(fmaxf(bf2f(v[j]) * k.x + k.y, 0.f));
    }
    *(u16x8*)(out1p + ((size_t)(n * PADR + (h + 1) * 58 + (w + 1))) * 128 + c0) = o;
}

// ---- BN2 + residual(bf16 x) + ReLU + NHWC->NCHW f32 ----
__global__ void bn_add_relu_nchw(const u16* __restrict__ y2, const float2* __restrict__ coef,
                                 const u16* __restrict__ xbp, float* __restrict__ out) {
    __shared__ float tile[32][65];
    __shared__ float2 sc[32];
    const int t = threadIdx.x;
    const int n = blockIdx.y;
    const int ct = blockIdx.x & 3;
    const int pt = blockIdx.x >> 2;
    const int c0 = ct * 32, p0 = pt * 64;
    if (t < 32) sc[t] = coef[c0 + t];
    __syncthreads();
    {
        const int pl = t >> 2;
        const int cs = (t & 3) * 8;
        const int p  = p0 + pl;
        const int h  = p / 56;
        const int w  = p - h * 56;
        const u16x8 v = *(const u16x8*)(y2 + ((size_t)(n * HW + p)) * 128 + c0 + cs);
        const u16x8 xv = *(const u16x8*)(xbp +
            ((size_t)(n * PADR + (h + 1) * 58 + (w + 1))) * 128 + c0 + cs);
#pragma unroll
        for (int j = 0; j < 8; ++j) {
            float2 k = sc[cs + j];
            tile[cs + j][pl] = bf2f(v[j]) * k.x + k.y + bf2f(xv[j]);
        }
    }
    __syncthreads();
    {
        const int c  = t >> 3;
        const int pw = (t & 7) * 8;
        const size_t ob = ((size_t)(n * 128 + c0 + c)) * HW + p0 + pw;
        float4 o0, o1;
        o0.x = fmaxf(tile[c][pw + 0], 0.f);
        o0.y = fmaxf(tile[c][pw + 1], 0.f);
        o0.z = fmaxf(tile[c][pw + 2], 0.f);
        o0.w = fmaxf(tile[c][pw + 3], 0.f);
        o1.x = fmaxf(tile[c][pw + 4], 0.f);
        o1.y = fmaxf(tile[c][pw + 5], 0.f);
        o1.z = fmaxf(tile[c][pw + 6], 0.f);
        o1.w = fmaxf(tile[c][pw + 7], 0.f);
        *(float4*)(out + ob) = o0;
        *(float4*)(out + ob + 4) = o1;
    }
}

extern "C" void kernel_launch(void* const* d_in, const int* in_sizes, int n_in,
                              void* d_out, int out_size, void* d_ws, size_t ws_size,
                              hipStream_t stream) {
    const float* x  = (const float*)d_in[0];
    const float* w1 = (const float*)d_in[1];
    const float* g1 = (const float*)d_in[2];
    const float* b1 = (const float*)d_in[3];
    const float* w2 = (const float*)d_in[4];
    const float* g2 = (const float*)d_in[5];
    const float* b2 = (const float*)d_in[6];
    float* out = (float*)d_out;
    char* ws = (char*)d_ws;

    u16*    xbp   = (u16*)(ws);                        // padded NHWC x (bf16), kept live
    u16*    ybuf  = (u16*)(ws + 27557888);             // conv out NHWC bf16
    u16*    Bm1   = (u16*)(ws + 53248000);
    u16*    Bm2   = (u16*)(ws + 53542912);
    float2* part  = (float2*)(ws + 53837824);          // 128 x 784 float2 = 802816 B
    float2* cf1   = (float2*)(ws + 54640640);
    float2* cf2   = (float2*)(ws + 54641664);
    int*    cnts  = (int*)(ws + 54642688);             // 2 counters
    u16*    out1p = (u16*)d_out;                       // padded out1 bf16, overwritten by final kernel

    int* cnt1 = cnts;
    int* cnt2 = cnts + 1;

    setup_kernel<<<2065, 256, 0, stream>>>(w1, w2, Bm1, Bm2, xbp, out1p, cnts);
    x_to_nhwc<<<dim3(196, 32), 256, 0, stream>>>(x, xbp);

    conv_mfma<<<NBLK, 256, 0, stream>>>(xbp, Bm1, ybuf, part, g1, b1, cf1, cnt1);
    bnrelu_kernel<<<6272, 256, 0, stream>>>(ybuf, cf1, out1p);

    conv_mfma<<<NBLK, 256, 0, stream>>>(out1p, Bm2, ybuf, part, g2, b2, cf2, cnt2);
    bn_add_relu_nchw<<<dim3(196, 32), 256, 0, stream>>>(ybuf, cf2, xbp, out);
}

// Round 12
// 143.765 us; speedup vs baseline: 2.4901x; 2.4901x over previous
//
#include <hip/hip_runtime.h>

typedef unsigned short u16;
typedef unsigned short u16x8 __attribute__((ext_vector_type(8)));
typedef __bf16 bf16x8 __attribute__((ext_vector_type(8)));
typedef float f32x4 __attribute__((ext_vector_type(4)));

#define HW 3136        // 56*56
#define NPIX 100352    // 32*3136
#define PADR 3364      // 58*58 padded rows per image
#define KD 1152        // 9*128
#define NBLK 784

__device__ __forceinline__ float bf2f(u16 u) {
    unsigned int x = ((unsigned int)u) << 16;
    return __builtin_bit_cast(float, x);
}
__device__ __forceinline__ u16 f2bf(float f) {
    unsigned int u = __builtin_bit_cast(unsigned int, f);
    return (u16)((u + 0x7FFFu + ((u >> 16) & 1u)) >> 16);
}
__device__ __forceinline__ void gload16(const void* g, void* l) {
    __builtin_amdgcn_global_load_lds(
        (const __attribute__((address_space(1))) unsigned int*)g,
        (__attribute__((address_space(3))) unsigned int*)l, 16, 0, 0);
}

// ---- setup: binarize weights + zero xbp/out1p borders + x -> padded NHWC bf16 ----
__global__ void setup_kernel(const float* __restrict__ w1, const float* __restrict__ w2,
                             u16* __restrict__ Bm1, u16* __restrict__ Bm2,
                             u16* __restrict__ xbp, u16* __restrict__ out1p,
                             const float* __restrict__ x) {
    __shared__ float tile[32][65];
    const int b = blockIdx.x;
    const int t = threadIdx.x;
    if (b < 1152) {
        const float* w = (b < 576) ? w1 : w2;
        u16* Bm = (b < 576) ? Bm1 : Bm2;
        int i = (b % 576) * 256 + t;
        int k  = i / KD;
        int kk = i - k * KD;
        int c  = kk & 127;
        int rs = kk >> 7;
        float v = w[(size_t)(k * 128 + c) * 9 + rs];
        float sv = (v > 0.f) ? 1.f : ((v < 0.f) ? -1.f : 0.f);
        Bm[i] = f2bf(sv);
        return;
    }
    if (b < 2064) {
        const bool toOut = (b >= 1608);
        u16* dst = toOut ? out1p : xbp;
        int idx = ((toOut ? b - 1608 : b - 1152)) * 256 + t;   // < 116736 exactly
        int pix = idx >> 4;
        int cc  = idx & 15;
        int n  = pix / 228;
        int pb = pix - n * 228;
        int h, w;
        if (pb < 58)       { h = 0;  w = pb; }
        else if (pb < 116) { h = 57; w = pb - 58; }
        else { int q = pb - 116; h = 1 + (q >> 1); w = (q & 1) ? 57 : 0; }
        u16x8 z = {};
        *(u16x8*)(dst + ((size_t)(n * PADR + h * 58 + w)) * 128 + cc * 8) = z;
        return;
    }
    // x_to_nhwc: 6272 blocks (bijective remap of dim3(196,32))
    {
        const int idx = b - 2064;
        const int bx = idx % 196;
        const int n  = idx / 196;
        const int ct = bx & 3;
        const int pt = bx >> 2;
        const int c0 = ct * 32, p0 = pt * 64;
        {
            const int c  = t >> 3;
            const int pw = (t & 7) * 8;
            const size_t ib = ((size_t)(n * 128 + c0 + c)) * HW + p0 + pw;
            const float4 v0 = *(const float4*)(x + ib);
            const float4 v1 = *(const float4*)(x + ib + 4);
            tile[c][pw + 0] = v0.x; tile[c][pw + 1] = v0.y;
            tile[c][pw + 2] = v0.z; tile[c][pw + 3] = v0.w;
            tile[c][pw + 4] = v1.x; tile[c][pw + 5] = v1.y;
            tile[c][pw + 6] = v1.z; tile[c][pw + 7] = v1.w;
        }
        __syncthreads();
        {
            const int pl = t >> 2;
            const int cs = (t & 3) * 8;
            const int p  = p0 + pl;
            const int h  = p / 56;
            const int w  = p - h * 56;
            u16x8 o;
#pragma unroll
            for (int j = 0; j < 8; ++j) o[j] = f2bf(tile[cs + j][pl]);
            *(u16x8*)(xbp + ((size_t)(n * PADR + (h + 1) * 58 + (w + 1))) * 128 + c0 + cs) = o;
        }
    }
}

// ---- conv implicit GEMM, m97-structure (R5 verbatim): single-buffered BK=64, 4 blocks/CU ----
__global__ __launch_bounds__(256, 4) void conv_mfma(
    const u16* __restrict__ xbp, const u16* __restrict__ Bm,
    u16* __restrict__ y, float2* __restrict__ partial)
{
    __shared__ __align__(16) u16 smem[20480];   // 40960 B -> 4 blocks/CU
    u16* As = smem;            // [128 rows][64 ch] = 16 KB
    u16* Bs = smem + 8192;     // [128 rows][64 ch] = 16 KB
    const int t = threadIdx.x;
    const int bid0 = blockIdx.x;
    const int bid = (bid0 & 7) * 98 + (bid0 >> 3);   // XCD swizzle, 784 = 8*98 bijective
    const int pm0 = bid * 128;
    const int wid  = t >> 6;
    const int lane = t & 63;
    const int lrow = lane & 15;
    const int lhk  = lane >> 4;
    const int m0 = (wid >> 1) * 64;
    const int n0 = (wid & 1) * 64;

    // staging: instr j covers 8-row group g=wid*4+j; lane -> row g*8+(lane>>3),
    // dest chunk lane&7 (linear), source chunk (lane&7)^(lane>>3) (inverse swizzle)
    const int rsub = lane >> 3;
    const int csrc = (lane & 7) ^ rsub;
    int apix[4], bbase[4];
#pragma unroll
    for (int j = 0; j < 4; ++j) {
        int row = (wid * 4 + j) * 8 + rsub;
        int ps  = pm0 + row;
        int n   = ps / HW;
        int rem = ps - n * HW;
        int h   = rem / 56;
        int w   = rem - h * 56;
        apix[j]  = (n * PADR + (h + 1) * 58 + (w + 1)) * 128 + csrc * 8;
        bbase[j] = row * KD + csrc * 8;
    }

    f32x4 acc[4][4] = {};

#pragma unroll 1
    for (int pp = 0; pp < 18; ++pp) {
        const int rs_ = pp >> 1;
        const int r_ = rs_ / 3, s_ = rs_ - r_ * 3;
        const int ash = ((r_ - 1) * 58 + (s_ - 1)) * 128 + (pp & 1) * 64;
        const int bsh = pp * 64;
#pragma unroll
        for (int j = 0; j < 4; ++j) {
            gload16(xbp + apix[j] + ash, As + (wid * 4 + j) * 512);
            gload16(Bm + bbase[j] + bsh, Bs + (wid * 4 + j) * 512);
        }
        __syncthreads();
#pragma unroll
        for (int kc = 0; kc < 2; ++kc) {
            bf16x8 af[4], bv[4];
#pragma unroll
            for (int mi = 0; mi < 4; ++mi) {
                int ck = (((kc << 2) | lhk) ^ (lrow & 7)) << 3;
                af[mi] = *(const bf16x8*)&As[(m0 + mi * 16 + lrow) * 64 + ck];
            }
#pragma unroll
            for (int ni = 0; ni < 4; ++ni) {
                int ck = (((kc << 2) | lhk) ^ (lrow & 7)) << 3;
                bv[ni] = *(const bf16x8*)&Bs[(n0 + ni * 16 + lrow) * 64 + ck];
            }
#pragma unroll
            for (int mi = 0; mi < 4; ++mi)
#pragma unroll
                for (int ni = 0; ni < 4; ++ni)
                    acc[mi][ni] = __builtin_amdgcn_mfma_f32_16x16x32_bf16(
                        af[mi], bv[ni], acc[mi][ni], 0, 0, 0);
        }
        __syncthreads();
    }

    // --- fused per-block BN stats
    float2* sred = (float2*)(smem + 17408);   // byte 34816..36863, past transpose tile
    {
        float sv[4], qv[4];
#pragma unroll
        for (int ni = 0; ni < 4; ++ni) {
            float a = 0.f, b = 0.f;
#pragma unroll
            for (int mi = 0; mi < 4; ++mi)
#pragma unroll
                for (int q = 0; q < 4; ++q) { float v = acc[mi][ni][q]; a += v; b += v * v; }
            a += __shfl_xor(a, 16); a += __shfl_xor(a, 32);
            b += __shfl_xor(b, 16); b += __shfl_xor(b, 32);
            sv[ni] = a; qv[ni] = b;
        }
        if (lane < 16) {
#pragma unroll
            for (int ni = 0; ni < 4; ++ni)
                sred[wid * 64 + ni * 16 + lane] = make_float2(sv[ni], qv[ni]);
        }
    }

    // --- transpose acc -> [128 px][136 pad] bf16 (34816 B), coalesced store
#pragma unroll
    for (int mi = 0; mi < 4; ++mi)
#pragma unroll
        for (int ni = 0; ni < 4; ++ni)
#pragma unroll
            for (int q = 0; q < 4; ++q)
                smem[(m0 + mi * 16 + lhk * 4 + q) * 136 + n0 + ni * 16 + lrow] =
                    f2bf(acc[mi][ni][q]);
    __syncthreads();
    {
        const int px = t >> 1, half = t & 1;
        const u16* src = &smem[px * 136 + half * 64];
        u16* dst = y + (size_t)(pm0 + px) * 128 + half * 64;
#pragma unroll
        for (int j = 0; j < 8; ++j)
            *(u16x8*)(dst + j * 8) = *(const u16x8*)(src + j * 8);
    }
    if (t < 128) {
        const int ni = (t >> 4) & 3, oc = t & 15, hi = t >> 6;
        float2 u = sred[hi * 64 + ni * 16 + oc];
        float2 v = sred[(hi + 2) * 64 + ni * 16 + oc];
        partial[(size_t)t * NBLK + bid] = make_float2(u.x + v.x, u.y + v.y);
    }
}

// ---- reduce partials -> BN coef (a,b): y' = a*y + b ----
__global__ void stats_finalize(const float2* __restrict__ partial,
                               const float* __restrict__ gamma, const float* __restrict__ beta,
                               float2* __restrict__ coef) {
    __shared__ float ss[256], ss2[256];
    const int c = blockIdx.x, t = threadIdx.x;
    const float2* pc = partial + (size_t)c * NBLK;
    float s = 0.f, s2 = 0.f;
    for (int i = t; i < NBLK; i += 256) { float2 v = pc[i]; s += v.x; s2 += v.y; }
    ss[t] = s; ss2[t] = s2;
    __syncthreads();
    for (int o = 128; o > 0; o >>= 1) {
        if (t < o) { ss[t] += ss[t + o]; ss2[t] += ss2[t + o]; }
        __syncthreads();
    }
    if (t == 0) {
        double mean = (double)ss[0] / (double)NPIX;
        double var  = (double)ss2[0] / (double)NPIX - mean * mean;
        if (var < 0.0) var = 0.0;
        float inv = rsqrtf((float)var + 1e-5f);
        float a = gamma[c] * inv;
        coef[c] = make_float2(a, beta[c] - (float)mean * a);
    }
}

// ---- BN1 + ReLU: y (linear NHWC) -> padded NHWC bf16 out1p (interior only) ----
__global__ void bnrelu_kernel(const u16* __restrict__ y, const float2* __restrict__ coef,
                              u16* __restrict__ out1p) {
    __shared__ float2 sc[128];
    const int t = threadIdx.x;
    if (t < 128) sc[t] = coef[t];
    __syncthreads();
    size_t i = (size_t)blockIdx.x * 256 + t;
    u16x8 v = *(const u16x8*)(y + i * 8);
    int p  = (int)(i >> 4);
    int c0 = (int)(i & 15) * 8;
    int n   = p / HW;
    int rem = p - n * HW;
    int h   = rem / 56;
    int w   = rem - h * 56;
    u16x8 o;
#pragma unroll
    for (int j = 0; j < 8; ++j) {
        float2 k = sc[c0 + j];
        o[j] = f2bf(fmaxf(bf2f(v[j]) * k.x + k.y, 0.f));
    }
    *(u16x8*)(out1p + ((size_t)(n * PADR + (h + 1) * 58 + (w + 1))) * 128 + c0) = o;
}

// ---- BN2 + residual(bf16 x) + ReLU + NHWC->NCHW f32 ----
__global__ void bn_add_relu_nchw(const u16* __restrict__ y2, const float2* __restrict__ coef,
                                 const u16* __restrict__ xbp, float* __restrict__ out) {
    __shared__ float tile[32][65];
    __shared__ float2 sc[32];
    const int t = threadIdx.x;
    const int n = blockIdx.y;
    const int ct = blockIdx.x & 3;
    const int pt = blockIdx.x >> 2;
    const int c0 = ct * 32, p0 = pt * 64;
    if (t < 32) sc[t] = coef[c0 + t];
    __syncthreads();
    {
        const int pl = t >> 2;
        const int cs = (t & 3) * 8;
        const int p  = p0 + pl;
        const int h  = p / 56;
        const int w  = p - h * 56;
        const u16x8 v = *(const u16x8*)(y2 + ((size_t)(n * HW + p)) * 128 + c0 + cs);
        const u16x8 xv = *(const u16x8*)(xbp +
            ((size_t)(n * PADR + (h + 1) * 58 + (w + 1))) * 128 + c0 + cs);
#pragma unroll
        for (int j = 0; j < 8; ++j) {
            float2 k = sc[cs + j];
            tile[cs + j][pl] = bf2f(v[j]) * k.x + k.y + bf2f(xv[j]);
        }
    }
    __syncthreads();
    {
        const int c  = t >> 3;
        const int pw = (t & 7) * 8;
        const size_t ob = ((size_t)(n * 128 + c0 + c)) * HW + p0 + pw;
        float4 o0, o1;
        o0.x = fmaxf(tile[c][pw + 0], 0.f);
        o0.y = fmaxf(tile[c][pw + 1], 0.f);
        o0.z = fmaxf(tile[c][pw + 2], 0.f);
        o0.w = fmaxf(tile[c][pw + 3], 0.f);
        o1.x = fmaxf(tile[c][pw + 4], 0.f);
        o1.y = fmaxf(tile[c][pw + 5], 0.f);
        o1.z = fmaxf(tile[c][pw + 6], 0.f);
        o1.w = fmaxf(tile[c][pw + 7], 0.f);
        *(float4*)(out + ob) = o0;
        *(float4*)(out + ob + 4) = o1;
    }
}

extern "C" void kernel_launch(void* const* d_in, const int* in_sizes, int n_in,
                              void* d_out, int out_size, void* d_ws, size_t ws_size,
                              hipStream_t stream) {
    const float* x  = (const float*)d_in[0];
    const float* w1 = (const float*)d_in[1];
    const float* g1 = (const float*)d_in[2];
    const float* b1 = (const float*)d_in[3];
    const float* w2 = (const float*)d_in[4];
    const float* g2 = (const float*)d_in[5];
    const float* b2 = (const float*)d_in[6];
    float* out = (float*)d_out;
    char* ws = (char*)d_ws;

    u16*    xbp   = (u16*)(ws);                        // padded NHWC x (bf16), kept live
    u16*    ybuf  = (u16*)(ws + 27557888);             // conv out NHWC bf16
    u16*    Bm1   = (u16*)(ws + 53248000);
    u16*    Bm2   = (u16*)(ws + 53542912);
    float2* part  = (float2*)(ws + 53837824);          // 128 x 784 float2 = 802816 B
    float2* cf1   = (float2*)(ws + 54640640);
    float2* cf2   = (float2*)(ws + 54641664);
    u16*    out1p = (u16*)d_out;                       // padded out1 bf16, overwritten by final kernel

    setup_kernel<<<8336, 256, 0, stream>>>(w1, w2, Bm1, Bm2, xbp, out1p, x);

    conv_mfma<<<NBLK, 256, 0, stream>>>(xbp, Bm1, ybuf, part);
    stats_finalize<<<128, 256, 0, stream>>>(part, g1, b1, cf1);
    bnrelu_kernel<<<6272, 256, 0, stream>>>(ybuf, cf1, out1p);

    conv_mfma<<<NBLK, 256, 0, stream>>>(out1p, Bm2, ybuf, part);
    stats_finalize<<<128, 256, 0, stream>>>(part, g2, b2, cf2);
    bn_add_relu_nchw<<<dim3(196, 32), 256, 0, stream>>>(ybuf, cf2, xbp, out);
}

// Round 13
// 135.872 us; speedup vs baseline: 2.6348x; 1.0581x over previous
//
#include <hip/hip_runtime.h>

typedef unsigned short u16;
typedef unsigned short u16x8 __attribute__((ext_vector_type(8)));
typedef __bf16 bf16x8 __attribute__((ext_vector_type(8)));
typedef float f32x4 __attribute__((ext_vector_type(4)));

#define HW 3136        // 56*56
#define NPIX 100352    // 32*3136
#define PADR 3364      // 58*58 padded rows per image
#define KD 1152        // 9*128
#define NBLK 800       // 768 full (M=128) + 32 half (M=64)
#define NSLOT 800

__device__ __forceinline__ float bf2f(u16 u) {
    unsigned int x = ((unsigned int)u) << 16;
    return __builtin_bit_cast(float, x);
}
__device__ __forceinline__ u16 f2bf(float f) {
    unsigned int u = __builtin_bit_cast(unsigned int, f);
    return (u16)((u + 0x7FFFu + ((u >> 16) & 1u)) >> 16);
}
__device__ __forceinline__ void gload16(const void* g, void* l) {
    __builtin_amdgcn_global_load_lds(
        (const __attribute__((address_space(1))) unsigned int*)g,
        (__attribute__((address_space(3))) unsigned int*)l, 16, 0, 0);
}

// ---- setup: binarize weights + zero xbp/out1p borders + x -> padded NHWC bf16 ----
__global__ void setup_kernel(const float* __restrict__ w1, const float* __restrict__ w2,
                             u16* __restrict__ Bm1, u16* __restrict__ Bm2,
                             u16* __restrict__ xbp, u16* __restrict__ out1p,
                             const float* __restrict__ x) {
    __shared__ float tile[32][65];
    const int b = blockIdx.x;
    const int t = threadIdx.x;
    if (b < 1152) {
        const float* w = (b < 576) ? w1 : w2;
        u16* Bm = (b < 576) ? Bm1 : Bm2;
        int i = (b % 576) * 256 + t;
        int k  = i / KD;
        int kk = i - k * KD;
        int c  = kk & 127;
        int rs = kk >> 7;
        float v = w[(size_t)(k * 128 + c) * 9 + rs];
        float sv = (v > 0.f) ? 1.f : ((v < 0.f) ? -1.f : 0.f);
        Bm[i] = f2bf(sv);
        return;
    }
    if (b < 2064) {
        const bool toOut = (b >= 1608);
        u16* dst = toOut ? out1p : xbp;
        int idx = ((toOut ? b - 1608 : b - 1152)) * 256 + t;   // < 116736 exactly
        int pix = idx >> 4;
        int cc  = idx & 15;
        int n  = pix / 228;
        int pb = pix - n * 228;
        int h, w;
        if (pb < 58)       { h = 0;  w = pb; }
        else if (pb < 116) { h = 57; w = pb - 58; }
        else { int q = pb - 116; h = 1 + (q >> 1); w = (q & 1) ? 57 : 0; }
        u16x8 z = {};
        *(u16x8*)(dst + ((size_t)(n * PADR + h * 58 + w)) * 128 + cc * 8) = z;
        return;
    }
    // x_to_nhwc: 6272 blocks (bijective remap of dim3(196,32))
    {
        const int idx = b - 2064;
        const int bx = idx % 196;
        const int n  = idx / 196;
        const int ct = bx & 3;
        const int pt = bx >> 2;
        const int c0 = ct * 32, p0 = pt * 64;
        {
            const int c  = t >> 3;
            const int pw = (t & 7) * 8;
            const size_t ib = ((size_t)(n * 128 + c0 + c)) * HW + p0 + pw;
            const float4 v0 = *(const float4*)(x + ib);
            const float4 v1 = *(const float4*)(x + ib + 4);
            tile[c][pw + 0] = v0.x; tile[c][pw + 1] = v0.y;
            tile[c][pw + 2] = v0.z; tile[c][pw + 3] = v0.w;
            tile[c][pw + 4] = v1.x; tile[c][pw + 5] = v1.y;
            tile[c][pw + 6] = v1.z; tile[c][pw + 7] = v1.w;
        }
        __syncthreads();
        {
            const int pl = t >> 2;
            const int cs = (t & 3) * 8;
            const int p  = p0 + pl;
            const int h  = p / 56;
            const int w  = p - h * 56;
            u16x8 o;
#pragma unroll
            for (int j = 0; j < 8; ++j) o[j] = f2bf(tile[cs + j][pl]);
            *(u16x8*)(xbp + ((size_t)(n * PADR + (h + 1) * 58 + (w + 1))) * 128 + c0 + cs) = o;
        }
    }
}

// ---- conv body, m97-structure (R12 verbatim for MT=4; MT=2 = strict subset) ----
// MT = number of 16-row M-tiles per wave (4 -> M=128 block, 2 -> M=64 block)
template<int MT>
__device__ __forceinline__ void conv_body(
    const int pm0, const int slot,
    const u16* __restrict__ xbp, const u16* __restrict__ Bm,
    u16* __restrict__ y, float2* __restrict__ partial, u16* smem)
{
    u16* As = smem;            // [MT*32 rows][64 ch]
    u16* Bs = smem + 8192;     // [128 rows][64 ch]
    const int t = threadIdx.x;
    const int wid  = t >> 6;
    const int lane = t & 63;
    const int lrow = lane & 15;
    const int lhk  = lane >> 4;
    const int m0 = (wid >> 1) * (MT * 16);
    const int n0 = (wid & 1) * 64;

    // staging: A group g = wid*MT+j covers rows g*8+(lane>>3); dest chunk lane&7
    // (linear), source chunk (lane&7)^(lane>>3) (inverse swizzle). Wave-uniform dests.
    const int rsub = lane >> 3;
    const int csrc = (lane & 7) ^ rsub;
    int apix[MT], bbase[4];
#pragma unroll
    for (int j = 0; j < MT; ++j) {
        int row = (wid * MT + j) * 8 + rsub;
        int ps  = pm0 + row;
        int n   = ps / HW;
        int rem = ps - n * HW;
        int h   = rem / 56;
        int w   = rem - h * 56;
        apix[j] = (n * PADR + (h + 1) * 58 + (w + 1)) * 128 + csrc * 8;
    }
#pragma unroll
    for (int j = 0; j < 4; ++j)
        bbase[j] = ((wid * 4 + j) * 8 + rsub) * KD + csrc * 8;

    f32x4 acc[MT][4] = {};

#pragma unroll 1
    for (int pp = 0; pp < 18; ++pp) {
        const int rs_ = pp >> 1;
        const int r_ = rs_ / 3, s_ = rs_ - r_ * 3;
        const int ash = ((r_ - 1) * 58 + (s_ - 1)) * 128 + (pp & 1) * 64;
        const int bsh = pp * 64;
#pragma unroll
        for (int j = 0; j < MT; ++j)
            gload16(xbp + apix[j] + ash, As + (wid * MT + j) * 512);
#pragma unroll
        for (int j = 0; j < 4; ++j)
            gload16(Bm + bbase[j] + bsh, Bs + (wid * 4 + j) * 512);
        __syncthreads();
#pragma unroll
        for (int kc = 0; kc < 2; ++kc) {
            bf16x8 af[MT], bv[4];
#pragma unroll
            for (int mi = 0; mi < MT; ++mi) {
                int ck = (((kc << 2) | lhk) ^ (lrow & 7)) << 3;
                af[mi] = *(const bf16x8*)&As[(m0 + mi * 16 + lrow) * 64 + ck];
            }
#pragma unroll
            for (int ni = 0; ni < 4; ++ni) {
                int ck = (((kc << 2) | lhk) ^ (lrow & 7)) << 3;
                bv[ni] = *(const bf16x8*)&Bs[(n0 + ni * 16 + lrow) * 64 + ck];
            }
#pragma unroll
            for (int mi = 0; mi < MT; ++mi)
#pragma unroll
                for (int ni = 0; ni < 4; ++ni)
                    acc[mi][ni] = __builtin_amdgcn_mfma_f32_16x16x32_bf16(
                        af[mi], bv[ni], acc[mi][ni], 0, 0, 0);
        }
        __syncthreads();
    }

    // --- fused per-block BN stats
    float2* sred = (float2*)(smem + 17408);   // bytes 34816..36863
    {
        float sv[4], qv[4];
#pragma unroll
        for (int ni = 0; ni < 4; ++ni) {
            float a = 0.f, b = 0.f;
#pragma unroll
            for (int mi = 0; mi < MT; ++mi)
#pragma unroll
                for (int q = 0; q < 4; ++q) { float v = acc[mi][ni][q]; a += v; b += v * v; }
            a += __shfl_xor(a, 16); a += __shfl_xor(a, 32);
            b += __shfl_xor(b, 16); b += __shfl_xor(b, 32);
            sv[ni] = a; qv[ni] = b;
        }
        if (lane < 16) {
#pragma unroll
            for (int ni = 0; ni < 4; ++ni)
                sred[wid * 64 + ni * 16 + lane] = make_float2(sv[ni], qv[ni]);
        }
    }

    // --- transpose acc -> [MT*32 px][136 pad] bf16, coalesced store
#pragma unroll
    for (int mi = 0; mi < MT; ++mi)
#pragma unroll
        for (int ni = 0; ni < 4; ++ni)
#pragma unroll
            for (int q = 0; q < 4; ++q)
                smem[(m0 + mi * 16 + lhk * 4 + q) * 136 + n0 + ni * 16 + lrow] =
                    f2bf(acc[mi][ni][q]);
    __syncthreads();
    if constexpr (MT == 4) {
        const int px = t >> 1, half = t & 1;
        const u16* src = &smem[px * 136 + half * 64];
        u16* dst = y + (size_t)(pm0 + px) * 128 + half * 64;
#pragma unroll
        for (int j = 0; j < 8; ++j)
            *(u16x8*)(dst + j * 8) = *(const u16x8*)(src + j * 8);
    } else {
        const int px = t >> 2, q4 = t & 3;        // 64 px, 32 u16 per thread
        const u16* src = &smem[px * 136 + q4 * 32];
        u16* dst = y + (size_t)(pm0 + px) * 128 + q4 * 32;
#pragma unroll
        for (int j = 0; j < 4; ++j)
            *(u16x8*)(dst + j * 8) = *(const u16x8*)(src + j * 8);
    }
    if (t < 128) {
        const int ni = (t >> 4) & 3, oc = t & 15, hi = t >> 6;
        float2 u = sred[hi * 64 + ni * 16 + oc];
        float2 v = sred[(hi + 2) * 64 + ni * 16 + oc];
        partial[(size_t)t * NSLOT + slot] = make_float2(u.x + v.x, u.y + v.y);
    }
}

__global__ __launch_bounds__(256, 4) void conv_mfma(
    const u16* __restrict__ xbp, const u16* __restrict__ Bm,
    u16* __restrict__ y, float2* __restrict__ partial)
{
    __shared__ __align__(16) u16 smem[20480];   // 40960 B -> 4 blocks/CU
    const int bid0 = blockIdx.x;
    if (bid0 < 768) {
        const int bid = (bid0 & 7) * 96 + (bid0 >> 3);   // XCD swizzle, 768 = 8*96 bijective
        conv_body<4>(bid * 128, bid, xbp, Bm, y, partial, smem);
    } else {
        const int e = bid0 - 768;                         // 32 half-tiles, dispatched last
        conv_body<2>(98304 + e * 64, 768 + e, xbp, Bm, y, partial, smem);
    }
}

// ---- reduce partials -> BN coef (a,b): y' = a*y + b ----
__global__ void stats_finalize(const float2* __restrict__ partial,
                               const float* __restrict__ gamma, const float* __restrict__ beta,
                               float2* __restrict__ coef) {
    __shared__ float ss[256], ss2[256];
    const int c = blockIdx.x, t = threadIdx.x;
    const float2* pc = partial + (size_t)c * NSLOT;
    float s = 0.f, s2 = 0.f;
    for (int i = t; i < NSLOT; i += 256) { float2 v = pc[i]; s += v.x; s2 += v.y; }
    ss[t] = s; ss2[t] = s2;
    __syncthreads();
    for (int o = 128; o > 0; o >>= 1) {
        if (t < o) { ss[t] += ss[t + o]; ss2[t] += ss2[t + o]; }
        __syncthreads();
    }
    if (t == 0) {
        double mean = (double)ss[0] / (double)NPIX;
        double var  = (double)ss2[0] / (double)NPIX - mean * mean;
        if (var < 0.0) var = 0.0;
        float inv = rsqrtf((float)var + 1e-5f);
        float a = gamma[c] * inv;
        coef[c] = make_float2(a, beta[c] - (float)mean * a);
    }
}

// ---- BN1 + ReLU: y (linear NHWC) -> padded NHWC bf16 out1p (interior only) ----
__global__ void bnrelu_kernel(const u16* __restrict__ y, const float2* __restrict__ coef,
                              u16* __restrict__ out1p) {
    __shared__ float2 sc[128];
    const int t = threadIdx.x;
    if (t < 128) sc[t] = coef[t];
    __syncthreads();
    size_t i = (size_t)blockIdx.x * 256 + t;
    u16x8 v = *(const u16x8*)(y + i * 8);
    int p  = (int)(i >> 4);
    int c0 = (int)(i & 15) * 8;
    int n   = p / HW;
    int rem = p - n * HW;
    int h   = rem / 56;
    int w   = rem - h * 56;
    u16x8 o;
#pragma unroll
    for (int j = 0; j < 8; ++j) {
        float2 k = sc[c0 + j];
        o[j] = f2bf(fmaxf(bf2f(v[j]) * k.x + k.y, 0.f));
    }
    *(u16x8*)(out1p + ((size_t)(n * PADR + (h + 1) * 58 + (w + 1))) * 128 + c0) = o;
}

// ---- BN2 + residual(bf16 x) + ReLU + NHWC->NCHW f32 ----
__global__ void bn_add_relu_nchw(const u16* __restrict__ y2, const float2* __restrict__ coef,
                                 const u16* __restrict__ xbp, float* __restrict__ out) {
    __shared__ float tile[32][65];
    __shared__ float2 sc[32];
    const int t = threadIdx.x;
    const int n = blockIdx.y;
    const int ct = blockIdx.x & 3;
    const int pt = blockIdx.x >> 2;
    const int c0 = ct * 32, p0 = pt * 64;
    if (t < 32) sc[t] = coef[c0 + t];
    __syncthreads();
    {
        const int pl = t >> 2;
        const int cs = (t & 3) * 8;
        const int p  = p0 + pl;
        const int h  = p / 56;
        const int w  = p - h * 56;
        const u16x8 v = *(const u16x8*)(y2 + ((size_t)(n * HW + p)) * 128 + c0 + cs);
        const u16x8 xv = *(const u16x8*)(xbp +
            ((size_t)(n * PADR + (h + 1) * 58 + (w + 1))) * 128 + c0 + cs);
#pragma unroll
        for (int j = 0; j < 8; ++j) {
            float2 k = sc[cs + j];
            tile[cs + j][pl] = bf2f(v[j]) * k.x + k.y + bf2f(xv[j]);
        }
    }
    __syncthreads();
    {
        const int c  = t >> 3;
        const int pw = (t & 7) * 8;
        const size_t ob = ((size_t)(n * 128 + c0 + c)) * HW + p0 + pw;
        float4 o0, o1;
        o0.x = fmaxf(tile[c][pw + 0], 0.f);
        o0.y = fmaxf(tile[c][pw + 1], 0.f);
        o0.z = fmaxf(tile[c][pw + 2], 0.f);
        o0.w = fmaxf(tile[c][pw + 3], 0.f);
        o1.x = fmaxf(tile[c][pw + 4], 0.f);
        o1.y = fmaxf(tile[c][pw + 5], 0.f);
        o1.z = fmaxf(tile[c][pw + 6], 0.f);
        o1.w = fmaxf(tile[c][pw + 7], 0.f);
        *(float4*)(out + ob) = o0;
        *(float4*)(out + ob + 4) = o1;
    }
}

extern "C" void kernel_launch(void* const* d_in, const int* in_sizes, int n_in,
                              void* d_out, int out_size, void* d_ws, size_t ws_size,
                              hipStream_t stream) {
    const float* x  = (const float*)d_in[0];
    const float* w1 = (const float*)d_in[1];
    const float* g1 = (const float*)d_in[2];
    const float* b1 = (const float*)d_in[3];
    const float* w2 = (const float*)d_in[4];
    const float* g2 = (const float*)d_in[5];
    const float* b2 = (const float*)d_in[6];
    float* out = (float*)d_out;
    char* ws = (char*)d_ws;

    u16*    xbp   = (u16*)(ws);                        // padded NHWC x (bf16), kept live
    u16*    ybuf  = (u16*)(ws + 27557888);             // conv out NHWC bf16
    u16*    Bm1   = (u16*)(ws + 53248000);
    u16*    Bm2   = (u16*)(ws + 53542912);
    float2* part  = (float2*)(ws + 53837824);          // 128 x 800 float2 = 819200 B
    float2* cf1   = (float2*)(ws + 54657024);
    float2* cf2   = (float2*)(ws + 54658048);
    u16*    out1p = (u16*)d_out;                       // padded out1 bf16, overwritten by final kernel

    setup_kernel<<<8336, 256, 0, stream>>>(w1, w2, Bm1, Bm2, xbp, out1p, x);

    conv_mfma<<<NBLK, 256, 0, stream>>>(xbp, Bm1, ybuf, part);
    stats_finalize<<<128, 256, 0, stream>>>(part, g1, b1, cf1);
    bnrelu_kernel<<<6272, 256, 0, stream>>>(ybuf, cf1, out1p);

    conv_mfma<<<NBLK, 256, 0, stream>>>(out1p, Bm2, ybuf, part);
    stats_finalize<<<128, 256, 0, stream>>>(part, g2, b2, cf2);
    bn_add_relu_nchw<<<dim3(196, 32), 256, 0, stream>>>(ybuf, cf2, xbp, out);
}

// Round 14
// 133.317 us; speedup vs baseline: 2.6853x; 1.0192x over previous
//
#include <hip/hip_runtime.h>

typedef unsigned short u16;
typedef unsigned short u16x8 __attribute__((ext_vector_type(8)));
typedef __bf16 bf16x8 __attribute__((ext_vector_type(8)));
typedef float f32x4 __attribute__((ext_vector_type(4)));

#define HW 3136        // 56*56
#define NPIX 100352    // 32*3136
#define PADR 3364      // 58*58 padded rows per image
#define KD 1152        // 9*128
#define NBLK 832       // 768 full (M=128) + 64 quarter (M=32)
#define NSLOT 832

__device__ __forceinline__ float bf2f(u16 u) {
    unsigned int x = ((unsigned int)u) << 16;
    return __builtin_bit_cast(float, x);
}
__device__ __forceinline__ u16 f2bf(float f) {
    unsigned int u = __builtin_bit_cast(unsigned int, f);
    return (u16)((u + 0x7FFFu + ((u >> 16) & 1u)) >> 16);
}
__device__ __forceinline__ void gload16(const void* g, void* l) {
    __builtin_amdgcn_global_load_lds(
        (const __attribute__((address_space(1))) unsigned int*)g,
        (__attribute__((address_space(3))) unsigned int*)l, 16, 0, 0);
}

// ---- setup: binarize weights + zero xbp/out1p borders + x -> padded NHWC bf16 ----
__global__ void setup_kernel(const float* __restrict__ w1, const float* __restrict__ w2,
                             u16* __restrict__ Bm1, u16* __restrict__ Bm2,
                             u16* __restrict__ xbp, u16* __restrict__ out1p,
                             const float* __restrict__ x) {
    __shared__ float tile[32][65];
    const int b = blockIdx.x;
    const int t = threadIdx.x;
    if (b < 1152) {
        const float* w = (b < 576) ? w1 : w2;
        u16* Bm = (b < 576) ? Bm1 : Bm2;
        int i = (b % 576) * 256 + t;
        int k  = i / KD;
        int kk = i - k * KD;
        int c  = kk & 127;
        int rs = kk >> 7;
        float v = w[(size_t)(k * 128 + c) * 9 + rs];
        float sv = (v > 0.f) ? 1.f : ((v < 0.f) ? -1.f : 0.f);
        Bm[i] = f2bf(sv);
        return;
    }
    if (b < 2064) {
        const bool toOut = (b >= 1608);
        u16* dst = toOut ? out1p : xbp;
        int idx = ((toOut ? b - 1608 : b - 1152)) * 256 + t;   // < 116736 exactly
        int pix = idx >> 4;
        int cc  = idx & 15;
        int n  = pix / 228;
        int pb = pix - n * 228;
        int h, w;
        if (pb < 58)       { h = 0;  w = pb; }
        else if (pb < 116) { h = 57; w = pb - 58; }
        else { int q = pb - 116; h = 1 + (q >> 1); w = (q & 1) ? 57 : 0; }
        u16x8 z = {};
        *(u16x8*)(dst + ((size_t)(n * PADR + h * 58 + w)) * 128 + cc * 8) = z;
        return;
    }
    // x_to_nhwc: 6272 blocks (bijective remap of dim3(196,32))
    {
        const int idx = b - 2064;
        const int bx = idx % 196;
        const int n  = idx / 196;
        const int ct = bx & 3;
        const int pt = bx >> 2;
        const int c0 = ct * 32, p0 = pt * 64;
        {
            const int c  = t >> 3;
            const int pw = (t & 7) * 8;
            const size_t ib = ((size_t)(n * 128 + c0 + c)) * HW + p0 + pw;
            const float4 v0 = *(const float4*)(x + ib);
            const float4 v1 = *(const float4*)(x + ib + 4);
            tile[c][pw + 0] = v0.x; tile[c][pw + 1] = v0.y;
            tile[c][pw + 2] = v0.z; tile[c][pw + 3] = v0.w;
            tile[c][pw + 4] = v1.x; tile[c][pw + 5] = v1.y;
            tile[c][pw + 6] = v1.z; tile[c][pw + 7] = v1.w;
        }
        __syncthreads();
        {
            const int pl = t >> 2;
            const int cs = (t & 3) * 8;
            const int p  = p0 + pl;
            const int h  = p / 56;
            const int w  = p - h * 56;
            u16x8 o;
#pragma unroll
            for (int j = 0; j < 8; ++j) o[j] = f2bf(tile[cs + j][pl]);
            *(u16x8*)(xbp + ((size_t)(n * PADR + (h + 1) * 58 + (w + 1))) * 128 + c0 + cs) = o;
        }
    }
}

// ---- conv body, m97-structure (R12/R13 verbatim for MT=4; MT<4 strict subsets) ----
// MT = number of 16-row M-tiles per wave (4 -> M=128 block, 2 -> M=64, 1 -> M=32)
template<int MT>
__device__ __forceinline__ void conv_body(
    const int pm0, const int slot,
    const u16* __restrict__ xbp, const u16* __restrict__ Bm,
    u16* __restrict__ y, float2* __restrict__ partial, u16* smem)
{
    u16* As = smem;            // [MT*32 rows][64 ch]
    u16* Bs = smem + 8192;     // [128 rows][64 ch]
    const int t = threadIdx.x;
    const int wid  = t >> 6;
    const int lane = t & 63;
    const int lrow = lane & 15;
    const int lhk  = lane >> 4;
    const int m0 = (wid >> 1) * (MT * 16);
    const int n0 = (wid & 1) * 64;

    // staging: A group g = wid*MT+j covers rows g*8+(lane>>3); dest chunk lane&7
    // (linear), source chunk (lane&7)^(lane>>3) (inverse swizzle). Wave-uniform dests.
    const int rsub = lane >> 3;
    const int csrc = (lane & 7) ^ rsub;
    int apix[MT], bbase[4];
#pragma unroll
    for (int j = 0; j < MT; ++j) {
        int row = (wid * MT + j) * 8 + rsub;
        int ps  = pm0 + row;
        int n   = ps / HW;
        int rem = ps - n * HW;
        int h   = rem / 56;
        int w   = rem - h * 56;
        apix[j] = (n * PADR + (h + 1) * 58 + (w + 1)) * 128 + csrc * 8;
    }
#pragma unroll
    for (int j = 0; j < 4; ++j)
        bbase[j] = ((wid * 4 + j) * 8 + rsub) * KD + csrc * 8;

    f32x4 acc[MT][4] = {};

#pragma unroll 1
    for (int pp = 0; pp < 18; ++pp) {
        const int rs_ = pp >> 1;
        const int r_ = rs_ / 3, s_ = rs_ - r_ * 3;
        const int ash = ((r_ - 1) * 58 + (s_ - 1)) * 128 + (pp & 1) * 64;
        const int bsh = pp * 64;
#pragma unroll
        for (int j = 0; j < MT; ++j)
            gload16(xbp + apix[j] + ash, As + (wid * MT + j) * 512);
#pragma unroll
        for (int j = 0; j < 4; ++j)
            gload16(Bm + bbase[j] + bsh, Bs + (wid * 4 + j) * 512);
        __syncthreads();
#pragma unroll
        for (int kc = 0; kc < 2; ++kc) {
            bf16x8 af[MT], bv[4];
#pragma unroll
            for (int mi = 0; mi < MT; ++mi) {
                int ck = (((kc << 2) | lhk) ^ (lrow & 7)) << 3;
                af[mi] = *(const bf16x8*)&As[(m0 + mi * 16 + lrow) * 64 + ck];
            }
#pragma unroll
            for (int ni = 0; ni < 4; ++ni) {
                int ck = (((kc << 2) | lhk) ^ (lrow & 7)) << 3;
                bv[ni] = *(const bf16x8*)&Bs[(n0 + ni * 16 + lrow) * 64 + ck];
            }
#pragma unroll
            for (int mi = 0; mi < MT; ++mi)
#pragma unroll
                for (int ni = 0; ni < 4; ++ni)
                    acc[mi][ni] = __builtin_amdgcn_mfma_f32_16x16x32_bf16(
                        af[mi], bv[ni], acc[mi][ni], 0, 0, 0);
        }
        __syncthreads();
    }

    // --- fused per-block BN stats (lane mapping MT-independent)
    float2* sred = (float2*)(smem + 17408);   // bytes 34816..36863
    {
        float sv[4], qv[4];
#pragma unroll
        for (int ni = 0; ni < 4; ++ni) {
            float a = 0.f, b = 0.f;
#pragma unroll
            for (int mi = 0; mi < MT; ++mi)
#pragma unroll
                for (int q = 0; q < 4; ++q) { float v = acc[mi][ni][q]; a += v; b += v * v; }
            a += __shfl_xor(a, 16); a += __shfl_xor(a, 32);
            b += __shfl_xor(b, 16); b += __shfl_xor(b, 32);
            sv[ni] = a; qv[ni] = b;
        }
        if (lane < 16) {
#pragma unroll
            for (int ni = 0; ni < 4; ++ni)
                sred[wid * 64 + ni * 16 + lane] = make_float2(sv[ni], qv[ni]);
        }
    }

    // --- transpose acc -> [MT*32 px][136 pad] bf16, coalesced store
#pragma unroll
    for (int mi = 0; mi < MT; ++mi)
#pragma unroll
        for (int ni = 0; ni < 4; ++ni)
#pragma unroll
            for (int q = 0; q < 4; ++q)
                smem[(m0 + mi * 16 + lhk * 4 + q) * 136 + n0 + ni * 16 + lrow] =
                    f2bf(acc[mi][ni][q]);
    __syncthreads();
    if constexpr (MT == 4) {
        const int px = t >> 1, half = t & 1;
        const u16* src = &smem[px * 136 + half * 64];
        u16* dst = y + (size_t)(pm0 + px) * 128 + half * 64;
#pragma unroll
        for (int j = 0; j < 8; ++j)
            *(u16x8*)(dst + j * 8) = *(const u16x8*)(src + j * 8);
    } else if constexpr (MT == 2) {
        const int px = t >> 2, q4 = t & 3;        // 64 px, 32 u16 per thread
        const u16* src = &smem[px * 136 + q4 * 32];
        u16* dst = y + (size_t)(pm0 + px) * 128 + q4 * 32;
#pragma unroll
        for (int j = 0; j < 4; ++j)
            *(u16x8*)(dst + j * 8) = *(const u16x8*)(src + j * 8);
    } else {                                      // MT == 1: 32 px, 16 u16 per thread
        const int px = t >> 3, off = (t & 7) * 16;
        const u16* src = &smem[px * 136 + off];
        u16* dst = y + (size_t)(pm0 + px) * 128 + off;
        *(u16x8*)(dst)     = *(const u16x8*)(src);
        *(u16x8*)(dst + 8) = *(const u16x8*)(src + 8);
    }
    if (t < 128) {
        const int ni = (t >> 4) & 3, oc = t & 15, hi = t >> 6;
        float2 u = sred[hi * 64 + ni * 16 + oc];
        float2 v = sred[(hi + 2) * 64 + ni * 16 + oc];
        partial[(size_t)t * NSLOT + slot] = make_float2(u.x + v.x, u.y + v.y);
    }
}

__global__ __launch_bounds__(256, 4) void conv_mfma(
    const u16* __restrict__ xbp, const u16* __restrict__ Bm,
    u16* __restrict__ y, float2* __restrict__ partial)
{
    __shared__ __align__(16) u16 smem[20480];   // 40960 B -> 4 blocks/CU
    const int bid0 = blockIdx.x;
    if (bid0 < 768) {
        const int bid = (bid0 & 7) * 96 + (bid0 >> 3);   // XCD swizzle, 768 = 8*96 bijective
        conv_body<4>(bid * 128, bid, xbp, Bm, y, partial, smem);
    } else {
        const int e = bid0 - 768;                         // 64 quarter-tiles, dispatched last
        conv_body<1>(98304 + e * 32, 768 + e, xbp, Bm, y, partial, smem);
    }
}

// ---- reduce partials -> BN coef (a,b): y' = a*y + b ----
__global__ void stats_finalize(const float2* __restrict__ partial,
                               const float* __restrict__ gamma, const float* __restrict__ beta,
                               float2* __restrict__ coef) {
    __shared__ float ss[256], ss2[256];
    const int c = blockIdx.x, t = threadIdx.x;
    const float2* pc = partial + (size_t)c * NSLOT;
    float s = 0.f, s2 = 0.f;
    for (int i = t; i < NSLOT; i += 256) { float2 v = pc[i]; s += v.x; s2 += v.y; }
    ss[t] = s; ss2[t] = s2;
    __syncthreads();
    for (int o = 128; o > 0; o >>= 1) {
        if (t < o) { ss[t] += ss[t + o]; ss2[t] += ss2[t + o]; }
        __syncthreads();
    }
    if (t == 0) {
        double mean = (double)ss[0] / (double)NPIX;
        double var  = (double)ss2[0] / (double)NPIX - mean * mean;
        if (var < 0.0) var = 0.0;
        float inv = rsqrtf((float)var + 1e-5f);
        float a = gamma[c] * inv;
        coef[c] = make_float2(a, beta[c] - (float)mean * a);
    }
}

// ---- BN1 + ReLU: y (linear NHWC) -> padded NHWC bf16 out1p (interior only) ----
__global__ void bnrelu_kernel(const u16* __restrict__ y, const float2* __restrict__ coef,
                              u16* __restrict__ out1p) {
    __shared__ float2 sc[128];
    const int t = threadIdx.x;
    if (t < 128) sc[t] = coef[t];
    __syncthreads();
    size_t i = (size_t)blockIdx.x * 256 + t;
    u16x8 v = *(const u16x8*)(y + i * 8);
    int p  = (int)(i >> 4);
    int c0 = (int)(i & 15) * 8;
    int n   = p / HW;
    int rem = p - n * HW;
    int h   = rem / 56;
    int w   = rem - h * 56;
    u16x8 o;
#pragma unroll
    for (int j = 0; j < 8; ++j) {
        float2 k = sc[c0 + j];
        o[j] = f2bf(fmaxf(bf2f(v[j]) * k.x + k.y, 0.f));
    }
    *(u16x8*)(out1p + ((size_t)(n * PADR + (h + 1) * 58 + (w + 1))) * 128 + c0) = o;
}

// ---- BN2 + residual(bf16 x) + ReLU + NHWC->NCHW f32 ----
__global__ void bn_add_relu_nchw(const u16* __restrict__ y2, const float2* __restrict__ coef,
                                 const u16* __restrict__ xbp, float* __restrict__ out) {
    __shared__ float tile[32][65];
    __shared__ float2 sc[32];
    const int t = threadIdx.x;
    const int n = blockIdx.y;
    const int ct = blockIdx.x & 3;
    const int pt = blockIdx.x >> 2;
    const int c0 = ct * 32, p0 = pt * 64;
    if (t < 32) sc[t] = coef[c0 + t];
    __syncthreads();
    {
        const int pl = t >> 2;
        const int cs = (t & 3) * 8;
        const int p  = p0 + pl;
        const int h  = p / 56;
        const int w  = p - h * 56;
        const u16x8 v = *(const u16x8*)(y2 + ((size_t)(n * HW + p)) * 128 + c0 + cs);
        const u16x8 xv = *(const u16x8*)(xbp +
            ((size_t)(n * PADR + (h + 1) * 58 + (w + 1))) * 128 + c0 + cs);
#pragma unroll
        for (int j = 0; j < 8; ++j) {
            float2 k = sc[cs + j];
            tile[cs + j][pl] = bf2f(v[j]) * k.x + k.y + bf2f(xv[j]);
        }
    }
    __syncthreads();
    {
        const int c  = t >> 3;
        const int pw = (t & 7) * 8;
        const size_t ob = ((size_t)(n * 128 + c0 + c)) * HW + p0 + pw;
        float4 o0, o1;
        o0.x = fmaxf(tile[c][pw + 0], 0.f);
        o0.y = fmaxf(tile[c][pw + 1], 0.f);
        o0.z = fmaxf(tile[c][pw + 2], 0.f);
        o0.w = fmaxf(tile[c][pw + 3], 0.f);
        o1.x = fmaxf(tile[c][pw + 4], 0.f);
        o1.y = fmaxf(tile[c][pw + 5], 0.f);
        o1.z = fmaxf(tile[c][pw + 6], 0.f);
        o1.w = fmaxf(tile[c][pw + 7], 0.f);
        *(float4*)(out + ob) = o0;
        *(float4*)(out + ob + 4) = o1;
    }
}

extern "C" void kernel_launch(void* const* d_in, const int* in_sizes, int n_in,
                              void* d_out, int out_size, void* d_ws, size_t ws_size,
                              hipStream_t stream) {
    const float* x  = (const float*)d_in[0];
    const float* w1 = (const float*)d_in[1];
    const float* g1 = (const float*)d_in[2];
    const float* b1 = (const float*)d_in[3];
    const float* w2 = (const float*)d_in[4];
    const float* g2 = (const float*)d_in[5];
    const float* b2 = (const float*)d_in[6];
    float* out = (float*)d_out;
    char* ws = (char*)d_ws;

    u16*    xbp   = (u16*)(ws);                        // padded NHWC x (bf16), kept live
    u16*    ybuf  = (u16*)(ws + 27557888);             // conv out NHWC bf16
    u16*    Bm1   = (u16*)(ws + 53248000);
    u16*    Bm2   = (u16*)(ws + 53542912);
    float2* part  = (float2*)(ws + 53837824);          // 128 x 832 float2 = 851968 B
    float2* cf1   = (float2*)(ws + 54689792);
    float2* cf2   = (float2*)(ws + 54690816);
    u16*    out1p = (u16*)d_out;                       // padded out1 bf16, overwritten by final kernel

    setup_kernel<<<8336, 256, 0, stream>>>(w1, w2, Bm1, Bm2, xbp, out1p, x);

    conv_mfma<<<NBLK, 256, 0, stream>>>(xbp, Bm1, ybuf, part);
    stats_finalize<<<128, 256, 0, stream>>>(part, g1, b1, cf1);
    bnrelu_kernel<<<6272, 256, 0, stream>>>(ybuf, cf1, out1p);

    conv_mfma<<<NBLK, 256, 0, stream>>>(out1p, Bm2, ybuf, part);
    stats_finalize<<<128, 256, 0, stream>>>(part, g2, b2, cf2);
    bn_add_relu_nchw<<<dim3(196, 32), 256, 0, stream>>>(ybuf, cf2, xbp, out);
}